// Round 1
// baseline (307.147 us; speedup 1.0000x reference)
//
#include <hip/hip_runtime.h>

// Token reorderer: stable counting sort by expert id (64 experts).
// Outputs (all float32, concatenated in d_out):
//   [0, N)      scores in expert-sorted order
//   [N, 2N)     stable argsort permutation (as float; exact, N < 2^24)
//   [2N, 2N+64) tokens-per-expert histogram
//
// N = 8388608 (1M tokens x top_k 8), experts = 64 (hardcoded; ballot match uses 6 bits).

#define CPW 2048            // elements per wave
#define ROUNDS (CPW / 64)   // 32 rounds of 64 contiguous elements

__device__ __forceinline__ unsigned long long match_mask(
    unsigned key,
    unsigned long long b0, unsigned long long b1, unsigned long long b2,
    unsigned long long b3, unsigned long long b4, unsigned long long b5,
    unsigned long long am) {
  unsigned long long m = am;
  m &= (key & 1u)  ? b0 : ~b0;
  m &= (key & 2u)  ? b1 : ~b1;
  m &= (key & 4u)  ? b2 : ~b2;
  m &= (key & 8u)  ? b3 : ~b3;
  m &= (key & 16u) ? b4 : ~b4;
  m &= (key & 32u) ? b5 : ~b5;
  return m;
}

// Kernel 1: per-wave expert histogram -> countsT[expert][wave] (transposed).
__global__ __launch_bounds__(256) void hist_kernel(
    const int* __restrict__ idx, unsigned* __restrict__ countsT,
    int N, int Wp) {
  int gtid = blockIdx.x * blockDim.x + threadIdx.x;
  int wave = gtid >> 6;
  int lane = gtid & 63;
  long long start = (long long)wave * CPW;
  long long remain = (long long)N - start;
  unsigned cnt = 0;

  int full = 0;
  if (remain >= CPW) full = ROUNDS;
  else if (remain > 0) full = (int)(remain >> 6);

  #pragma unroll 4
  for (int r = 0; r < full; ++r) {
    long long i = start + (long long)r * 64 + lane;
    unsigned e = ((unsigned)idx[i]) & 63u;
    unsigned long long b0 = __ballot(e & 1u);
    unsigned long long b1 = __ballot(e & 2u);
    unsigned long long b2 = __ballot(e & 4u);
    unsigned long long b3 = __ballot(e & 8u);
    unsigned long long b4 = __ballot(e & 16u);
    unsigned long long b5 = __ballot(e & 32u);
    unsigned long long ml = match_mask((unsigned)lane, b0, b1, b2, b3, b4, b5, ~0ull);
    cnt += (unsigned)__popcll(ml);
  }
  // tail (partial round)
  if (full < ROUNDS && remain > (long long)full * 64) {
    long long i = start + (long long)full * 64 + lane;
    bool valid = i < (long long)N;
    unsigned long long am = __ballot(valid ? 1 : 0);
    unsigned e = valid ? (((unsigned)idx[i]) & 63u) : 0u;
    unsigned long long b0 = __ballot(e & 1u);
    unsigned long long b1 = __ballot(e & 2u);
    unsigned long long b2 = __ballot(e & 4u);
    unsigned long long b3 = __ballot(e & 8u);
    unsigned long long b4 = __ballot(e & 16u);
    unsigned long long b5 = __ballot(e & 32u);
    unsigned long long ml = match_mask((unsigned)lane, b0, b1, b2, b3, b4, b5, am);
    cnt += (unsigned)__popcll(ml);
  }
  countsT[(size_t)lane * Wp + wave] = cnt;
}

// Kernel 2: per-expert exclusive scan over waves (in place) + totals.
__global__ __launch_bounds__(256) void scan_kernel(
    unsigned* __restrict__ countsT, unsigned* __restrict__ totals,
    float* __restrict__ out_counts, int Wp) {
  int e = blockIdx.x;   // 0..63
  int t = threadIdx.x;  // 0..255
  unsigned* row = countsT + (size_t)e * Wp;
  int per = (Wp + 255) >> 8;
  int base = t * per;

  unsigned s = 0;
  for (int j = 0; j < per; ++j) {
    int w = base + j;
    if (w < Wp) s += row[w];
  }
  __shared__ unsigned sh[256];
  sh[t] = s;
  __syncthreads();
  for (int d = 1; d < 256; d <<= 1) {
    unsigned v = sh[t];
    unsigned add = (t >= d) ? sh[t - d] : 0u;
    __syncthreads();
    sh[t] = v + add;
    __syncthreads();
  }
  unsigned incl = sh[t];
  unsigned run = incl - s;  // exclusive offset for this thread's range
  for (int j = 0; j < per; ++j) {
    int w = base + j;
    if (w < Wp) { unsigned v = row[w]; row[w] = run; run += v; }
  }
  if (t == 255) {
    totals[e] = incl;             // total count for this expert
    out_counts[e] = (float)incl;  // output 2
  }
}

// Kernel 3: stable scatter using per-wave bases + in-round ballot ranks.
__global__ __launch_bounds__(256) void scatter_kernel(
    const int* __restrict__ idx, const float* __restrict__ scores,
    const unsigned* __restrict__ baseT, const unsigned* __restrict__ totals,
    float* __restrict__ out_scores, float* __restrict__ out_idx,
    int N, int Wp) {
  int gtid = blockIdx.x * blockDim.x + threadIdx.x;
  int wave = gtid >> 6;
  int lane = gtid & 63;

  // Cross-expert exclusive scan of totals (each wave recomputes; 6 shfl_up).
  unsigned tot = totals[lane];
  unsigned sum = tot;
  #pragma unroll
  for (int d = 1; d < 64; d <<= 1) {
    unsigned n = __shfl_up(sum, d, 64);
    if (lane >= d) sum += n;
  }
  unsigned expoff = sum - tot;

  // running[lane] = write cursor for expert==lane for this wave.
  unsigned running = baseT[(size_t)lane * Wp + wave] + expoff;

  long long start = (long long)wave * CPW;
  long long remain = (long long)N - start;
  if (remain <= 0) return;
  unsigned long long lt = (1ull << lane) - 1ull;

  int full = remain >= CPW ? ROUNDS : (int)(remain >> 6);

  #pragma unroll 4
  for (int r = 0; r < full; ++r) {
    long long i = start + (long long)r * 64 + lane;
    unsigned e = ((unsigned)idx[i]) & 63u;
    float s = scores[i];
    unsigned long long b0 = __ballot(e & 1u);
    unsigned long long b1 = __ballot(e & 2u);
    unsigned long long b2 = __ballot(e & 4u);
    unsigned long long b3 = __ballot(e & 8u);
    unsigned long long b4 = __ballot(e & 16u);
    unsigned long long b5 = __ballot(e & 32u);
    unsigned long long ms = match_mask(e, b0, b1, b2, b3, b4, b5, ~0ull);
    unsigned long long ml = match_mask((unsigned)lane, b0, b1, b2, b3, b4, b5, ~0ull);
    unsigned old = (unsigned)__shfl((int)running, (int)e, 64);
    unsigned pos = old + (unsigned)__popcll(ms & lt);
    running += (unsigned)__popcll(ml);
    out_scores[pos] = s;
    out_idx[pos] = (float)i;
  }
  // tail (partial round)
  if (full < ROUNDS && remain > (long long)full * 64) {
    long long i = start + (long long)full * 64 + lane;
    bool valid = i < (long long)N;
    unsigned long long am = __ballot(valid ? 1 : 0);
    unsigned e = valid ? (((unsigned)idx[i]) & 63u) : 0u;
    float s = valid ? scores[i] : 0.0f;
    unsigned long long b0 = __ballot(e & 1u);
    unsigned long long b1 = __ballot(e & 2u);
    unsigned long long b2 = __ballot(e & 4u);
    unsigned long long b3 = __ballot(e & 8u);
    unsigned long long b4 = __ballot(e & 16u);
    unsigned long long b5 = __ballot(e & 32u);
    unsigned long long ms = match_mask(e, b0, b1, b2, b3, b4, b5, am);
    unsigned long long ml = match_mask((unsigned)lane, b0, b1, b2, b3, b4, b5, am);
    unsigned old = (unsigned)__shfl((int)running, (int)e, 64);
    unsigned pos = old + (unsigned)__popcll(ms & lt);
    running += (unsigned)__popcll(ml);
    if (valid) {
      out_scores[pos] = s;
      out_idx[pos] = (float)i;
    }
  }
}

extern "C" void kernel_launch(void* const* d_in, const int* in_sizes, int n_in,
                              void* d_out, int out_size, void* d_ws, size_t ws_size,
                              hipStream_t stream) {
  const float* scores = (const float*)d_in[0];
  const int* idx = (const int*)d_in[1];
  int N = in_sizes[0];  // num_tokens * top_k = 8388608

  float* out_scores = (float*)d_out;       // [N]
  float* out_idx    = out_scores + N;      // [N]
  float* out_counts = out_idx + N;         // [64]

  int W = (N + CPW - 1) / CPW;             // waves needed
  int blocks = (W + 3) / 4;                // 256 threads = 4 waves/block
  int Wp = blocks * 4;                     // padded wave count (stride)

  unsigned* countsT = (unsigned*)d_ws;               // [64][Wp], scanned in place
  unsigned* totals  = countsT + (size_t)64 * Wp;     // [64]

  hist_kernel<<<blocks, 256, 0, stream>>>(idx, countsT, N, Wp);
  scan_kernel<<<64, 256, 0, stream>>>(countsT, totals, out_counts, Wp);
  scatter_kernel<<<blocks, 256, 0, stream>>>(idx, scores, countsT, totals,
                                             out_scores, out_idx, N, Wp);
}

// Round 2
// 173.878 us; speedup vs baseline: 1.7664x; 1.7664x over previous
//
#include <hip/hip_runtime.h>

// Token reorderer: stable counting sort by expert id (64 experts).
// Outputs (all float32, concatenated in d_out):
//   [0, N)      scores in expert-sorted order
//   [N, 2N)     stable argsort permutation (as float; exact, N < 2^24)
//   [2N, 2N+64) tokens-per-expert histogram
//
// R2: block-level LDS counting sort before global write to kill the 5.5x
// write amplification seen in R1 (WRITE_SIZE 368 MB vs 67 MB ideal).

#define B   4096           // elements per block (256 threads = 4 waves)
#define WCH 1024           // elements per wave chunk
#define RND (WCH / 64)     // 16 rounds of 64 contiguous elements per wave

__device__ __forceinline__ unsigned long long match_mask(
    unsigned key,
    unsigned long long b0, unsigned long long b1, unsigned long long b2,
    unsigned long long b3, unsigned long long b4, unsigned long long b5,
    unsigned long long am) {
  unsigned long long m = am;
  m &= (key & 1u)  ? b0 : ~b0;
  m &= (key & 2u)  ? b1 : ~b1;
  m &= (key & 4u)  ? b2 : ~b2;
  m &= (key & 8u)  ? b3 : ~b3;
  m &= (key & 16u) ? b4 : ~b4;
  m &= (key & 32u) ? b5 : ~b5;
  return m;
}

// Kernel 1: per-block expert histogram -> countsT[expert][block] (transposed).
__global__ __launch_bounds__(256) void hist_kernel(
    const int* __restrict__ idx, unsigned* __restrict__ countsT,
    int N, int nb) {
  __shared__ unsigned shc[4][64];
  int wave = threadIdx.x >> 6;
  int lane = threadIdx.x & 63;
  long long start = (long long)blockIdx.x * B + (long long)wave * WCH;
  long long remain = (long long)N - start;
  unsigned cnt = 0;

  int full = 0;
  if (remain >= WCH) full = RND;
  else if (remain > 0) full = (int)(remain >> 6);

  #pragma unroll 4
  for (int r = 0; r < full; ++r) {
    long long i = start + (long long)r * 64 + lane;
    unsigned e = ((unsigned)idx[i]) & 63u;
    unsigned long long b0 = __ballot(e & 1u);
    unsigned long long b1 = __ballot(e & 2u);
    unsigned long long b2 = __ballot(e & 4u);
    unsigned long long b3 = __ballot(e & 8u);
    unsigned long long b4 = __ballot(e & 16u);
    unsigned long long b5 = __ballot(e & 32u);
    cnt += (unsigned)__popcll(match_mask((unsigned)lane, b0, b1, b2, b3, b4, b5, ~0ull));
  }
  if (full < RND && remain > (long long)full * 64) {
    long long i = start + (long long)full * 64 + lane;
    bool valid = i < (long long)N;
    unsigned long long am = __ballot(valid ? 1 : 0);
    unsigned e = valid ? (((unsigned)idx[i]) & 63u) : 0u;
    unsigned long long b0 = __ballot(e & 1u);
    unsigned long long b1 = __ballot(e & 2u);
    unsigned long long b2 = __ballot(e & 4u);
    unsigned long long b3 = __ballot(e & 8u);
    unsigned long long b4 = __ballot(e & 16u);
    unsigned long long b5 = __ballot(e & 32u);
    cnt += (unsigned)__popcll(match_mask((unsigned)lane, b0, b1, b2, b3, b4, b5, am));
  }
  shc[wave][lane] = cnt;
  __syncthreads();
  if (threadIdx.x < 64) {
    unsigned s = shc[0][threadIdx.x] + shc[1][threadIdx.x] +
                 shc[2][threadIdx.x] + shc[3][threadIdx.x];
    countsT[(size_t)threadIdx.x * nb + blockIdx.x] = s;
  }
}

// Kernel 2: per-expert exclusive scan over blocks (in place) + totals.
__global__ __launch_bounds__(256) void scan_kernel(
    unsigned* __restrict__ countsT, unsigned* __restrict__ totals,
    float* __restrict__ out_counts, int nb) {
  int e = blockIdx.x;   // 0..63
  int t = threadIdx.x;  // 0..255
  unsigned* row = countsT + (size_t)e * nb;
  int per = (nb + 255) >> 8;
  int base = t * per;

  unsigned s = 0;
  for (int j = 0; j < per; ++j) {
    int w = base + j;
    if (w < nb) s += row[w];
  }
  __shared__ unsigned sh[256];
  sh[t] = s;
  __syncthreads();
  for (int d = 1; d < 256; d <<= 1) {
    unsigned v = sh[t];
    unsigned add = (t >= d) ? sh[t - d] : 0u;
    __syncthreads();
    sh[t] = v + add;
    __syncthreads();
  }
  unsigned incl = sh[t];
  unsigned run = incl - s;
  for (int j = 0; j < per; ++j) {
    int w = base + j;
    if (w < nb) { unsigned v = row[w]; row[w] = run; run += v; }
  }
  if (t == 255) {
    totals[e] = incl;
    out_counts[e] = (float)incl;
  }
}

// Kernel 3: block-local LDS counting sort, then coalesced per-expert writes.
__global__ __launch_bounds__(256) void scatter_kernel(
    const int* __restrict__ idx, const float* __restrict__ scores,
    const unsigned* __restrict__ baseT, const unsigned* __restrict__ totals,
    float* __restrict__ out_scores, float* __restrict__ out_idx,
    int N, int nb) {
  __shared__ unsigned shc[4][64];    // per-wave per-expert counts
  __shared__ unsigned shcur[4][64];  // per-wave starting cursor (block-local)
  __shared__ unsigned dbase[64];     // global dest = dbase[e] + local_pos
  __shared__ float    ssc[B];        // staged scores (expert-grouped order)
  __shared__ unsigned spk[B];        // staged (global_index << 6) | expert

  int wave = threadIdx.x >> 6;
  int lane = threadIdx.x & 63;
  long long start = (long long)blockIdx.x * B + (long long)wave * WCH;
  long long remain = (long long)N - start;
  unsigned long long lt = (1ull << lane) - 1ull;

  int full = 0;
  if (remain >= WCH) full = RND;
  else if (remain > 0) full = (int)(remain >> 6);

  // ---- Phase A: per-wave per-expert counts ----
  {
    unsigned cnt = 0;
    #pragma unroll 4
    for (int r = 0; r < full; ++r) {
      long long i = start + (long long)r * 64 + lane;
      unsigned e = ((unsigned)idx[i]) & 63u;
      unsigned long long b0 = __ballot(e & 1u);
      unsigned long long b1 = __ballot(e & 2u);
      unsigned long long b2 = __ballot(e & 4u);
      unsigned long long b3 = __ballot(e & 8u);
      unsigned long long b4 = __ballot(e & 16u);
      unsigned long long b5 = __ballot(e & 32u);
      cnt += (unsigned)__popcll(match_mask((unsigned)lane, b0, b1, b2, b3, b4, b5, ~0ull));
    }
    if (full < RND && remain > (long long)full * 64) {
      long long i = start + (long long)full * 64 + lane;
      bool valid = i < (long long)N;
      unsigned long long am = __ballot(valid ? 1 : 0);
      unsigned e = valid ? (((unsigned)idx[i]) & 63u) : 0u;
      unsigned long long b0 = __ballot(e & 1u);
      unsigned long long b1 = __ballot(e & 2u);
      unsigned long long b2 = __ballot(e & 4u);
      unsigned long long b3 = __ballot(e & 8u);
      unsigned long long b4 = __ballot(e & 16u);
      unsigned long long b5 = __ballot(e & 32u);
      cnt += (unsigned)__popcll(match_mask((unsigned)lane, b0, b1, b2, b3, b4, b5, am));
    }
    shc[wave][lane] = cnt;
  }
  __syncthreads();

  // ---- Phase B: block-local offsets + global dest bases (wave 0 only) ----
  if (threadIdx.x < 64) {
    int e = threadIdx.x;  // == lane
    unsigned c0 = shc[0][e], c1 = shc[1][e], c2 = shc[2][e], c3 = shc[3][e];
    unsigned bc = c0 + c1 + c2 + c3;

    // exclusive scan over experts (within wave 0) -> local_start[e]
    unsigned sum = bc;
    #pragma unroll
    for (int d = 1; d < 64; d <<= 1) {
      unsigned nv = __shfl_up(sum, d, 64);
      if (e >= d) sum += nv;
    }
    unsigned local_start = sum - bc;

    shcur[0][e] = local_start;
    shcur[1][e] = local_start + c0;
    shcur[2][e] = local_start + c0 + c1;
    shcur[3][e] = local_start + c0 + c1 + c2;

    // cross-expert exclusive scan of global totals
    unsigned tot = totals[e];
    unsigned s2 = tot;
    #pragma unroll
    for (int d = 1; d < 64; d <<= 1) {
      unsigned nv = __shfl_up(s2, d, 64);
      if (e >= d) s2 += nv;
    }
    unsigned expoff = s2 - tot;

    unsigned gb = baseT[(size_t)e * nb + blockIdx.x];
    dbase[e] = gb + expoff - local_start;  // u32 wraparound ok
  }
  __syncthreads();

  // ---- Phase C: stable scatter into LDS ----
  {
    unsigned running = shcur[wave][lane];  // cursor for expert == lane
    #pragma unroll 4
    for (int r = 0; r < full; ++r) {
      long long i = start + (long long)r * 64 + lane;
      unsigned e = ((unsigned)idx[i]) & 63u;
      float s = scores[i];
      unsigned long long b0 = __ballot(e & 1u);
      unsigned long long b1 = __ballot(e & 2u);
      unsigned long long b2 = __ballot(e & 4u);
      unsigned long long b3 = __ballot(e & 8u);
      unsigned long long b4 = __ballot(e & 16u);
      unsigned long long b5 = __ballot(e & 32u);
      unsigned long long ms = match_mask(e, b0, b1, b2, b3, b4, b5, ~0ull);
      unsigned long long ml = match_mask((unsigned)lane, b0, b1, b2, b3, b4, b5, ~0ull);
      unsigned old = (unsigned)__shfl((int)running, (int)e, 64);
      unsigned pos = old + (unsigned)__popcll(ms & lt);
      running += (unsigned)__popcll(ml);
      ssc[pos] = s;
      spk[pos] = (((unsigned)i) << 6) | e;  // i < 2^23
    }
    if (full < RND && remain > (long long)full * 64) {
      long long i = start + (long long)full * 64 + lane;
      bool valid = i < (long long)N;
      unsigned long long am = __ballot(valid ? 1 : 0);
      unsigned e = valid ? (((unsigned)idx[i]) & 63u) : 0u;
      float s = valid ? scores[i] : 0.0f;
      unsigned long long b0 = __ballot(e & 1u);
      unsigned long long b1 = __ballot(e & 2u);
      unsigned long long b2 = __ballot(e & 4u);
      unsigned long long b3 = __ballot(e & 8u);
      unsigned long long b4 = __ballot(e & 16u);
      unsigned long long b5 = __ballot(e & 32u);
      unsigned long long ms = match_mask(e, b0, b1, b2, b3, b4, b5, am);
      unsigned long long ml = match_mask((unsigned)lane, b0, b1, b2, b3, b4, b5, am);
      unsigned old = (unsigned)__shfl((int)running, (int)e, 64);
      unsigned pos = old + (unsigned)__popcll(ms & lt);
      running += (unsigned)__popcll(ml);
      if (valid) {
        ssc[pos] = s;
        spk[pos] = (((unsigned)i) << 6) | e;
      }
    }
  }
  __syncthreads();

  // ---- Phase D: coalesced write-out ----
  {
    long long bstart = (long long)blockIdx.x * B;
    int bvalid = (int)((N - bstart) < B ? (N - bstart) : B);
    for (int j = threadIdx.x; j < bvalid; j += 256) {
      unsigned p = spk[j];
      unsigned e = p & 63u;
      unsigned d = dbase[e] + (unsigned)j;
      out_scores[d] = ssc[j];
      out_idx[d] = (float)(p >> 6);
    }
  }
}

extern "C" void kernel_launch(void* const* d_in, const int* in_sizes, int n_in,
                              void* d_out, int out_size, void* d_ws, size_t ws_size,
                              hipStream_t stream) {
  const float* scores = (const float*)d_in[0];
  const int* idx = (const int*)d_in[1];
  int N = in_sizes[0];  // num_tokens * top_k = 8388608

  float* out_scores = (float*)d_out;       // [N]
  float* out_idx    = out_scores + N;      // [N]
  float* out_counts = out_idx + N;         // [64]

  int nb = (N + B - 1) / B;                // blocks (2048 for N=8388608)

  unsigned* countsT = (unsigned*)d_ws;             // [64][nb], scanned in place
  unsigned* totals  = countsT + (size_t)64 * nb;   // [64]

  hist_kernel<<<nb, 256, 0, stream>>>(idx, countsT, N, nb);
  scan_kernel<<<64, 256, 0, stream>>>(countsT, totals, out_counts, nb);
  scatter_kernel<<<nb, 256, 0, stream>>>(idx, scores, countsT, totals,
                                         out_scores, out_idx, N, nb);
}